// Round 7
// baseline (63.504 us; speedup 1.0000x reference)
//
#include <hip/hip_runtime.h>
#include <hip/hip_bf16.h>

// PatchNCELoss: N=16384 rows, D=256, B=4, P=4096 patches/batch.
// loss[n] = lse(row_logits) - pos_logit, logits = dots/T, diag masked to -10/T.
// bf16 MFMA flash-style fused GEMM+online-logsumexp in base-2 domain.
// Round 7: af=4 (64 rows/wave, 256-row blocks) with BN=32 so regs fit the
//          256-VGPR/2-waves-per-SIMD tier (round 4 spilled at BN=64).
//          LDS:MFMA per CU-step now 1024:2483 cyc -> LDS hideable.

typedef __attribute__((ext_vector_type(8))) short short8;
typedef __attribute__((ext_vector_type(4))) float f32x4;

#define BATCH 4
#define PN 4096
#define DD 256
#define NP (BATCH * PN)   // 16384 rows total

constexpr float kLog2e = 1.4426950408889634f;
constexpr float kScale = kLog2e / 0.07f;      // fold 1/T and log2(e) into Q
constexpr float kMask2 = -10.0f * kScale;     // masked diagonal logit (base-2)
constexpr float kLn2   = 0.6931471805599453f;
constexpr float kNegInf = -3.0e38f;

__device__ __forceinline__ unsigned short f2bf(float f) {
  __hip_bfloat16 h = __float2bfloat16(f);
  return *reinterpret_cast<unsigned short*>(&h);
}

// Native transcendentals: single v_exp_f32 / v_log_f32 (~1 ULP).
__device__ __forceinline__ float fexp2(float x) {
#if __has_builtin(__builtin_amdgcn_exp2f)
  return __builtin_amdgcn_exp2f(x);
#else
  return exp2f(x);
#endif
}
__device__ __forceinline__ float flog2(float x) {
#if __has_builtin(__builtin_amdgcn_logf)
  return __builtin_amdgcn_logf(x);
#else
  return log2f(x);
#endif
}

// ---------------- feat_k f32 -> bf16 conversion ----------------
__global__ void k_convert(const float* __restrict__ src,
                          unsigned short* __restrict__ dst, int n4) {
  int i = blockIdx.x * blockDim.x + threadIdx.x;
  if (i >= n4) return;
  float4 v = reinterpret_cast<const float4*>(src)[i];
  ushort4 o;
  o.x = f2bf(v.x); o.y = f2bf(v.y); o.z = f2bf(v.z); o.w = f2bf(v.w);
  reinterpret_cast<ushort4*>(dst)[i] = o;
}

// Stage a 32x256 bf16 K-tile (16384 B) global->LDS, linear LDS dest,
// XOR-swizzled global source; reader applies the same XOR. 256 threads.
__device__ __forceinline__ void stage16(const char* __restrict__ src,
                                        char* ldsbase, int tid) {
  const int wv = tid >> 6;
#pragma unroll
  for (int ip = 0; ip < 4; ip++) {
    const int o   = ip * 4096 + tid * 16;       // linear LDS byte offset
    const int row = o >> 9;                     // 512 B per K-row
    const int so  = o ^ ((row & 15) << 4);      // involution swizzle on source
    __builtin_amdgcn_global_load_lds(
        (const __attribute__((address_space(1))) void*)(src + so),
        (__attribute__((address_space(3))) void*)(ldsbase + ip * 4096 + wv * 1024),
        16, 0, 0);
  }
}

// Stage one 64x256 bf16 K-tile (32768 B) -- used by fallback kernels.
__device__ __forceinline__ void stage_tile(const char* __restrict__ src,
                                           char* ldsbase, int tid) {
  const int wv = tid >> 6;
#pragma unroll
  for (int ip = 0; ip < 8; ip++) {
    const int o   = ip * 4096 + tid * 16;
    const int row = o >> 9;
    const int so  = o ^ ((row & 15) << 4);
    __builtin_amdgcn_global_load_lds(
        (const __attribute__((address_space(1))) void*)(src + so),
        (__attribute__((address_space(3))) void*)(ldsbase + ip * 4096 + wv * 1024),
        16, 0, 0);
  }
}

// ================== main kernel: af=4, 512 blocks, 2/CU ==================
// blk -> b = blk&3, rt = (blk>>2)&15 (256-row tile), kc = blk>>6 (512-col chunk)
__global__ __launch_bounds__(256)
__attribute__((amdgpu_waves_per_eu(2, 2)))
void k_nce256(const float* __restrict__ fq, const unsigned short* __restrict__ kb,
              float* __restrict__ pl, float* __restrict__ pp) {
  __shared__ __align__(16) char kt[2][32 * 512];  // 2 x 16 KB double buffer

  const int blk = blockIdx.x;
  const int b   = blk & 3;
  const int r2  = blk >> 2;
  const int rt  = r2 & 15;           // 0..15 (256-row tiles)
  const int kc  = r2 >> 4;           // 0..7  (512-col chunks)
  const int R0  = rt * 256;
  const int C0  = kc * 512;
  const int tid = threadIdx.x;
  const int w   = tid >> 6;          // wave 0..3, owns rows [R0+64w, +64)
  const int l   = tid & 63;
  const int g   = l >> 4;
  const int li  = l & 15;

  const char* ksrc = reinterpret_cast<const char*>(kb) +
                     ((size_t)b * PN + C0) * 512;

  stage16(ksrc, kt[0], tid);   // overlap first stage with A-frag setup

  // ---- Q fragments: 64 rows/wave as 4 sets of 16; A row = li ----
  short8 a[4][8];
#pragma unroll
  for (int af = 0; af < 4; af++) {
    const float* qrow =
        fq + ((size_t)(b * PN + R0 + w * 64 + af * 16 + li)) * DD;
#pragma unroll
    for (int ks = 0; ks < 8; ks++) {
      const float* p = qrow + ks * 32 + g * 8;
      float4 v0 = *reinterpret_cast<const float4*>(p);
      float4 v1 = *reinterpret_cast<const float4*>(p + 4);
      a[af][ks][0] = (short)f2bf(v0.x * kScale);
      a[af][ks][1] = (short)f2bf(v0.y * kScale);
      a[af][ks][2] = (short)f2bf(v0.z * kScale);
      a[af][ks][3] = (short)f2bf(v0.w * kScale);
      a[af][ks][4] = (short)f2bf(v1.x * kScale);
      a[af][ks][5] = (short)f2bf(v1.y * kScale);
      a[af][ks][6] = (short)f2bf(v1.z * kScale);
      a[af][ks][7] = (short)f2bf(v1.w * kScale);
    }
  }

  float m[4][4], lsum[4][4];
#pragma unroll
  for (int af = 0; af < 4; af++)
#pragma unroll
    for (int r = 0; r < 4; r++) { m[af][r] = kNegInf; lsum[af][r] = 0.f; }

  __syncthreads();

  for (int ct = 0; ct < 16; ct++) {
    const int cur = ct & 1;
    if (ct + 1 < 16) stage16(ksrc + (size_t)(ct + 1) * 16384, kt[cur ^ 1], tid);

    const char* lb = kt[cur];
    f32x4 acc[4][2];
#pragma unroll
    for (int af = 0; af < 4; af++)
#pragma unroll
      for (int cf = 0; cf < 2; cf++) acc[af][cf] = f32x4{0.f, 0.f, 0.f, 0.f};

#pragma unroll
    for (int ks = 0; ks < 8; ks++) {
#pragma unroll
      for (int cf = 0; cf < 2; cf++) {
        const int row = cf * 16 + li;   // K-row (negative index in tile), 0..31
        const int off = row * 512 + ((ks * 64 + g * 16) ^ ((row & 15) << 4));
        short8 bf = *reinterpret_cast<const short8*>(lb + off);
#pragma unroll
        for (int af = 0; af < 4; af++)
          acc[af][cf] = __builtin_amdgcn_mfma_f32_16x16x32_bf16(a[af][ks], bf,
                                                                acc[af][cf], 0, 0, 0);
      }
    }

    // diagonal: row 16-block G = rt*16 + w*4 + af; col 16-block = kc*32 + ct*2 + cf.
    // Diag when G>>5==kc, ct == (G>>1)-kc*16, cf == G&1, li == g*4+r.
    // acc holds the FULL-D dot -> write positive logit straight to pp.
#pragma unroll
    for (int af = 0; af < 4; af++) {
      const int G = rt * 16 + w * 4 + af;
      if ((G >> 5) == kc && ct == ((G >> 1) - kc * 16)) {
        if ((G & 1) == 0) {
#pragma unroll
          for (int r = 0; r < 4; r++)
            if (li == g * 4 + r) {
              pp[b * PN + R0 + w * 64 + af * 16 + g * 4 + r] = acc[af][0][r];
              acc[af][0][r] = kMask2;
            }
        } else {
#pragma unroll
          for (int r = 0; r < 4; r++)
            if (li == g * 4 + r) {
              pp[b * PN + R0 + w * 64 + af * 16 + g * 4 + r] = acc[af][1][r];
              acc[af][1][r] = kMask2;
            }
        }
      }
    }

    // per-lane online logsumexp update
#pragma unroll
    for (int af = 0; af < 4; af++)
#pragma unroll
      for (int r = 0; r < 4; r++) {
        float v0 = acc[af][0][r], v1 = acc[af][1][r];
        float t0 = fmaxf(v0, v1);
        float mo = m[af][r];
        float mn = fmaxf(mo, t0);
        lsum[af][r] = lsum[af][r] * fexp2(mo - mn) + fexp2(v0 - mn) + fexp2(v1 - mn);
        m[af][r] = mn;
      }
    __syncthreads();
  }

  // merge 16 li-lanes per row, write chunk-partial LSE
#pragma unroll
  for (int af = 0; af < 4; af++)
#pragma unroll
    for (int r = 0; r < 4; r++) {
      float m_ = m[af][r], l_ = lsum[af][r];
#pragma unroll
      for (int off = 1; off < 16; off <<= 1) {
        float mo = __shfl_xor(m_, off, 64);
        float lo = __shfl_xor(l_, off, 64);
        float mn = fmaxf(m_, mo);
        l_ = l_ * fexp2(m_ - mn) + lo * fexp2(mo - mn);
        m_ = mn;
      }
      if (li == 0) {
        const int rowg = b * PN + R0 + w * 64 + af * 16 + g * 4 + r;
        pl[kc * NP + rowg] = m_ + flog2(l_);
      }
    }
}

// ================== combine: NC partials + pos -> loss ==================
template <int NC>
__global__ void k_combine(const float* __restrict__ pl,
                          const float* __restrict__ pp,
                          float* __restrict__ out) {
  const int i = blockIdx.x * blockDim.x + threadIdx.x;
  if (i >= NP) return;
  float mm = kNegInf;
  float v[NC];
#pragma unroll
  for (int c = 0; c < NC; c++) { v[c] = pl[c * NP + i]; mm = fmaxf(mm, v[c]); }
  float s = 0.f;
#pragma unroll
  for (int c = 0; c < NC; c++) s += fexp2(v[c] - mm);
  float lse = mm + flog2(s);
  float p = pp[i];
  float mn = fmaxf(lse, p);
  float la = mn + flog2(fexp2(lse - mn) + fexp2(p - mn));
  out[i] = (la - p) * kLn2;
}

// ================== fallback A: round-6 kernel (BN=32, af=2, 1024 blocks) ==================
__global__ __launch_bounds__(256, 4) void k_nce32(
    const float* __restrict__ fq, const unsigned short* __restrict__ kb,
    float* __restrict__ pl, float* __restrict__ pp) {
  __shared__ __align__(16) char kt[2][32 * 512];

  const int blk = blockIdx.x;
  const int b   = blk & 3;
  const int rt  = (blk >> 2) & 31;
  const int kc  = blk >> 7;
  const int R0  = rt * 128;
  const int C0  = kc * 512;
  const int tid = threadIdx.x;
  const int w   = tid >> 6;
  const int l   = tid & 63;
  const int g   = l >> 4;
  const int li  = l & 15;

  const char* ksrc = reinterpret_cast<const char*>(kb) +
                     ((size_t)b * PN + C0) * 512;
  stage16(ksrc, kt[0], tid);

  short8 a[2][8];
#pragma unroll
  for (int af = 0; af < 2; af++) {
    const float* qrow = fq + ((size_t)(b * PN + R0 + w * 32 + af * 16 + li)) * DD;
#pragma unroll
    for (int ks = 0; ks < 8; ks++) {
      const float* p = qrow + ks * 32 + g * 8;
      float4 v0 = *reinterpret_cast<const float4*>(p);
      float4 v1 = *reinterpret_cast<const float4*>(p + 4);
      a[af][ks][0] = (short)f2bf(v0.x * kScale); a[af][ks][1] = (short)f2bf(v0.y * kScale);
      a[af][ks][2] = (short)f2bf(v0.z * kScale); a[af][ks][3] = (short)f2bf(v0.w * kScale);
      a[af][ks][4] = (short)f2bf(v1.x * kScale); a[af][ks][5] = (short)f2bf(v1.y * kScale);
      a[af][ks][6] = (short)f2bf(v1.z * kScale); a[af][ks][7] = (short)f2bf(v1.w * kScale);
    }
  }

  float m[2][4], lsum[2][4];
#pragma unroll
  for (int af = 0; af < 2; af++)
#pragma unroll
    for (int r = 0; r < 4; r++) { m[af][r] = kNegInf; lsum[af][r] = 0.f; }

  const int ctd = (kc == (rt >> 2)) ? ((rt & 3) * 4 + w) : -1;
  __syncthreads();

  for (int ct = 0; ct < 16; ct++) {
    const int cur = ct & 1;
    if (ct + 1 < 16) stage16(ksrc + (size_t)(ct + 1) * 16384, kt[cur ^ 1], tid);

    const char* lb = kt[cur];
    f32x4 acc[2][2];
#pragma unroll
    for (int af = 0; af < 2; af++)
#pragma unroll
      for (int cf = 0; cf < 2; cf++) acc[af][cf] = f32x4{0.f, 0.f, 0.f, 0.f};

#pragma unroll
    for (int ks = 0; ks < 8; ks++) {
#pragma unroll
      for (int cf = 0; cf < 2; cf++) {
        const int row = cf * 16 + li;
        const int off = row * 512 + ((ks * 64 + g * 16) ^ ((row & 15) << 4));
        short8 bf = *reinterpret_cast<const short8*>(lb + off);
        acc[0][cf] = __builtin_amdgcn_mfma_f32_16x16x32_bf16(a[0][ks], bf, acc[0][cf], 0, 0, 0);
        acc[1][cf] = __builtin_amdgcn_mfma_f32_16x16x32_bf16(a[1][ks], bf, acc[1][cf], 0, 0, 0);
      }
    }

    if (ct == ctd) {
#pragma unroll
      for (int af = 0; af < 2; af++)
#pragma unroll
        for (int r = 0; r < 4; r++)
          if (li == g * 4 + r) {
            pp[b * PN + R0 + w * 32 + af * 16 + g * 4 + r] = acc[af][af][r];
            acc[af][af][r] = kMask2;
          }
    }

#pragma unroll
    for (int af = 0; af < 2; af++)
#pragma unroll
      for (int r = 0; r < 4; r++) {
        float v0 = acc[af][0][r], v1 = acc[af][1][r];
        float t0 = fmaxf(v0, v1);
        float mo = m[af][r];
        float mn = fmaxf(mo, t0);
        lsum[af][r] = lsum[af][r] * fexp2(mo - mn) + fexp2(v0 - mn) + fexp2(v1 - mn);
        m[af][r] = mn;
      }
    __syncthreads();
  }

#pragma unroll
  for (int af = 0; af < 2; af++)
#pragma unroll
    for (int r = 0; r < 4; r++) {
      float m_ = m[af][r], l_ = lsum[af][r];
#pragma unroll
      for (int off = 1; off < 16; off <<= 1) {
        float mo = __shfl_xor(m_, off, 64);
        float lo = __shfl_xor(l_, off, 64);
        float mn = fmaxf(m_, mo);
        l_ = l_ * fexp2(m_ - mn) + lo * fexp2(mo - mn);
        m_ = mn;
      }
      if (li == 0) {
        const int rowg = b * PN + R0 + w * 32 + af * 16 + g * 4 + r;
        pl[kc * NP + rowg] = m_ + flog2(l_);
      }
    }
}

// ================== fallback B: single-pass (needs only 8 MB ws) ==================
__global__ __launch_bounds__(256) void k_nce_full(const float* __restrict__ fq,
                                                  const unsigned short* __restrict__ kb,
                                                  float* __restrict__ out) {
  __shared__ __align__(16) char kt[2][64 * 512];
  const int blk = blockIdx.x;
  const int b = blk & 3, rt = blk >> 2;
  const int R0 = rt * 64;
  const int tid = threadIdx.x;
  const int w = tid >> 6, l = tid & 63, g = l >> 4, li = l & 15;

  const float* qrow = fq + ((size_t)(b * PN + R0 + w * 16 + li)) * DD;
  short8 a[8];
#pragma unroll
  for (int ks = 0; ks < 8; ks++) {
    const float* p = qrow + ks * 32 + g * 8;
    float4 v0 = *reinterpret_cast<const float4*>(p);
    float4 v1 = *reinterpret_cast<const float4*>(p + 4);
    a[ks][0] = (short)f2bf(v0.x * kScale); a[ks][1] = (short)f2bf(v0.y * kScale);
    a[ks][2] = (short)f2bf(v0.z * kScale); a[ks][3] = (short)f2bf(v0.w * kScale);
    a[ks][4] = (short)f2bf(v1.x * kScale); a[ks][5] = (short)f2bf(v1.y * kScale);
    a[ks][6] = (short)f2bf(v1.z * kScale); a[ks][7] = (short)f2bf(v1.w * kScale);
  }
  float m[4], lsum[4], pos[4];
#pragma unroll
  for (int r = 0; r < 4; r++) { m[r] = kNegInf; lsum[r] = 0.f; pos[r] = kNegInf; }
  const char* ksrc = reinterpret_cast<const char*>(kb + (size_t)b * PN * DD);
  stage_tile(ksrc, kt[0], tid);
  __syncthreads();
  for (int ct = 0; ct < 64; ct++) {
    const int cur = ct & 1;
    if (ct + 1 < 64) stage_tile(ksrc + (size_t)(ct + 1) * 32768, kt[cur ^ 1], tid);
    const char* lb = kt[cur];
    f32x4 acc[4];
#pragma unroll
    for (int cf = 0; cf < 4; cf++) acc[cf] = f32x4{0.f, 0.f, 0.f, 0.f};
#pragma unroll
    for (int ks = 0; ks < 8; ks++) {
#pragma unroll
      for (int cf = 0; cf < 4; cf++) {
        const int row = cf * 16 + li;
        const int off = row * 512 + ((ks * 64 + g * 16) ^ ((row & 15) << 4));
        short8 bf = *reinterpret_cast<const short8*>(lb + off);
        acc[cf] = __builtin_amdgcn_mfma_f32_16x16x32_bf16(a[ks], bf, acc[cf], 0, 0, 0);
      }
    }
    if (ct == rt) {
#pragma unroll
      for (int cf = 0; cf < 4; cf++)
        if (cf == w) {
#pragma unroll
          for (int r = 0; r < 4; r++)
            if (li == g * 4 + r) { pos[r] = acc[cf][r]; acc[cf][r] = kMask2; }
        }
    }
#pragma unroll
    for (int r = 0; r < 4; r++) {
      float t0 = fmaxf(fmaxf(acc[0][r], acc[1][r]), fmaxf(acc[2][r], acc[3][r]));
      float mo = m[r];
      float mn = fmaxf(mo, t0);
      float s = fexp2(acc[0][r] - mn) + fexp2(acc[1][r] - mn) +
                fexp2(acc[2][r] - mn) + fexp2(acc[3][r] - mn);
      lsum[r] = lsum[r] * fexp2(mo - mn) + s;
      m[r] = mn;
    }
    __syncthreads();
  }
#pragma unroll
  for (int r = 0; r < 4; r++) {
    float m_ = m[r], l_ = lsum[r], p_ = pos[r];
#pragma unroll
    for (int off = 1; off < 16; off <<= 1) {
      float mo = __shfl_xor(m_, off, 64);
      float lo = __shfl_xor(l_, off, 64);
      float po = __shfl_xor(p_, off, 64);
      float mn = fmaxf(m_, mo);
      l_ = l_ * fexp2(m_ - mn) + lo * fexp2(mo - mn);
      m_ = mn;
      p_ = fmaxf(p_, po);
    }
    float mn  = fmaxf(m_, p_);
    float lse = mn + flog2(l_ * fexp2(m_ - mn) + fexp2(p_ - mn));
    if (li == 0) out[b * PN + R0 + w * 16 + g * 4 + r] = (lse - p_) * kLn2;
  }
}

extern "C" void kernel_launch(void* const* d_in, const int* in_sizes, int n_in,
                              void* d_out, int out_size, void* d_ws, size_t ws_size,
                              hipStream_t stream) {
  const float* fq = (const float*)d_in[0];
  const float* fk = (const float*)d_in[1];
  float* out = (float*)d_out;
  unsigned short* kb = (unsigned short*)d_ws;          // 8 MB bf16 K
  const size_t kbBytes = (size_t)NP * DD * 2;          // 8388608
  const size_t ppBytes = (size_t)NP * 4;               // 65536
  const size_t pl8Bytes = (size_t)8 * NP * 4;          // 524288

  const int n4 = (NP * DD) / 4;
  hipLaunchKernelGGL(k_convert, dim3(n4 / 256), dim3(256), 0, stream, fk, kb, n4);

  if (ws_size >= kbBytes + pl8Bytes + ppBytes) {
    float* pl = (float*)((char*)d_ws + kbBytes);
    float* pp = (float*)((char*)d_ws + kbBytes + pl8Bytes);
    hipLaunchKernelGGL(k_nce256, dim3(512), dim3(256), 0, stream, fq, kb, pl, pp);
    hipLaunchKernelGGL(k_combine<8>, dim3(NP / 256), dim3(256), 0, stream, pl, pp, out);
  } else {
    hipLaunchKernelGGL(k_nce_full, dim3(BATCH * (PN / 64)), dim3(256), 0, stream,
                       fq, kb, out);
  }
}

// Round 8
// 58.690 us; speedup vs baseline: 1.0820x; 1.0820x over previous
//
#include <hip/hip_runtime.h>
#include <hip/hip_bf16.h>

// PatchNCELoss: N=16384 rows, D=256, B=4, P=4096 patches/batch.
// loss[n] = lse(row_logits) - pos_logit, logits = dots/T, diag masked to -10/T.
// bf16 MFMA flash-style fused GEMM+online-logsumexp in base-2 domain.
// Round 8: pre-convert Q (scale folded) to bf16 in ws; pin A-frags in VGPRs
//          via asm; 128-VGPR tier (4 waves/SIMD). Rounds 6/7 were secretly
//          re-converting Q from f32 every K-step (VGPR_Count 64/120 proved
//          A-frags were never resident).

typedef __attribute__((ext_vector_type(8))) short short8;
typedef __attribute__((ext_vector_type(4))) float f32x4;

#define BATCH 4
#define PN 4096
#define DD 256
#define NP (BATCH * PN)   // 16384 rows total

constexpr float kLog2e = 1.4426950408889634f;
constexpr float kScale = kLog2e / 0.07f;      // fold 1/T and log2(e) into Q
constexpr float kMask2 = -10.0f * kScale;     // masked diagonal logit (base-2)
constexpr float kLn2   = 0.6931471805599453f;
constexpr float kNegInf = -3.0e38f;

__device__ __forceinline__ unsigned short f2bf(float f) {
  __hip_bfloat16 h = __float2bfloat16(f);
  return *reinterpret_cast<unsigned short*>(&h);
}

// Native transcendentals: single v_exp_f32 / v_log_f32 (~1 ULP).
__device__ __forceinline__ float fexp2(float x) {
#if __has_builtin(__builtin_amdgcn_exp2f)
  return __builtin_amdgcn_exp2f(x);
#else
  return exp2f(x);
#endif
}
__device__ __forceinline__ float flog2(float x) {
#if __has_builtin(__builtin_amdgcn_logf)
  return __builtin_amdgcn_logf(x);
#else
  return log2f(x);
#endif
}

// -------- f32 -> bf16 conversion for BOTH q (scaled) and k ----------
__global__ void k_convert2(const float* __restrict__ fq,
                           const float* __restrict__ fk,
                           unsigned short* __restrict__ qb,
                           unsigned short* __restrict__ kb, int n4each) {
  int i = blockIdx.x * blockDim.x + threadIdx.x;
  if (i < n4each) {
    float4 v = reinterpret_cast<const float4*>(fq)[i];
    ushort4 o;
    o.x = f2bf(v.x * kScale); o.y = f2bf(v.y * kScale);
    o.z = f2bf(v.z * kScale); o.w = f2bf(v.w * kScale);
    reinterpret_cast<ushort4*>(qb)[i] = o;
  } else {
    int j = i - n4each;
    if (j >= n4each) return;
    float4 v = reinterpret_cast<const float4*>(fk)[j];
    ushort4 o;
    o.x = f2bf(v.x); o.y = f2bf(v.y); o.z = f2bf(v.z); o.w = f2bf(v.w);
    reinterpret_cast<ushort4*>(kb)[j] = o;
  }
}

// legacy single-buffer convert (fallback path)
__global__ void k_convert(const float* __restrict__ src,
                          unsigned short* __restrict__ dst, int n4) {
  int i = blockIdx.x * blockDim.x + threadIdx.x;
  if (i >= n4) return;
  float4 v = reinterpret_cast<const float4*>(src)[i];
  ushort4 o;
  o.x = f2bf(v.x); o.y = f2bf(v.y); o.z = f2bf(v.z); o.w = f2bf(v.w);
  reinterpret_cast<ushort4*>(dst)[i] = o;
}

// Stage a 32x256 bf16 K-tile (16384 B) global->LDS, linear LDS dest,
// XOR-swizzled global source; reader applies the same XOR. 256 threads.
__device__ __forceinline__ void stage16(const char* __restrict__ src,
                                        char* ldsbase, int tid) {
  const int wv = tid >> 6;
#pragma unroll
  for (int ip = 0; ip < 4; ip++) {
    const int o   = ip * 4096 + tid * 16;       // linear LDS byte offset
    const int row = o >> 9;                     // 512 B per K-row
    const int so  = o ^ ((row & 15) << 4);      // involution swizzle on source
    __builtin_amdgcn_global_load_lds(
        (const __attribute__((address_space(1))) void*)(src + so),
        (__attribute__((address_space(3))) void*)(ldsbase + ip * 4096 + wv * 1024),
        16, 0, 0);
  }
}

// Stage one 64x256 bf16 K-tile (32768 B) -- used by fallback kernel.
__device__ __forceinline__ void stage_tile(const char* __restrict__ src,
                                           char* ldsbase, int tid) {
  const int wv = tid >> 6;
#pragma unroll
  for (int ip = 0; ip < 8; ip++) {
    const int o   = ip * 4096 + tid * 16;
    const int row = o >> 9;
    const int so  = o ^ ((row & 15) << 4);
    __builtin_amdgcn_global_load_lds(
        (const __attribute__((address_space(1))) void*)(src + so),
        (__attribute__((address_space(3))) void*)(ldsbase + ip * 4096 + wv * 1024),
        16, 0, 0);
  }
}

// ================== main kernel: 1024 blocks, 4/CU, A resident ==================
// blk -> b = blk&3, rt = (blk>>2)&31 (128-row tile), kc = blk>>7 (512-col chunk)
__global__ __launch_bounds__(256)
__attribute__((amdgpu_waves_per_eu(4, 4)))
void k_nceQ(const unsigned short* __restrict__ qb,
            const unsigned short* __restrict__ kb,
            float* __restrict__ pl, float* __restrict__ pp) {
  __shared__ __align__(16) char kt[2][32 * 512];  // 2 x 16 KB double buffer

  const int blk = blockIdx.x;
  const int b   = blk & 3;
  const int rt  = (blk >> 2) & 31;   // 0..31 (128-row tiles)
  const int kc  = blk >> 7;          // 0..7  (512-col chunks)
  const int R0  = rt * 128;
  const int C0  = kc * 512;
  const int tid = threadIdx.x;
  const int w   = tid >> 6;          // wave 0..3, owns rows [R0+32w, +32)
  const int l   = tid & 63;
  const int g   = l >> 4;
  const int li  = l & 15;

  const char* ksrc = reinterpret_cast<const char*>(kb) +
                     ((size_t)b * PN + C0) * 512;

  stage16(ksrc, kt[0], tid);   // overlap first stage with A-frag setup

  // ---- Q fragments: 32 rows/wave as 2 sets of 16; A row = li.
  // Pre-converted, pre-scaled bf16 -> clean short8 loads; asm pin forces
  // register residency (compiler cannot rematerialize an asm output).
  short8 a[2][8];
#pragma unroll
  for (int af = 0; af < 2; af++) {
    const unsigned short* qrow =
        qb + (size_t)(b * PN + R0 + w * 32 + af * 16 + li) * DD;
#pragma unroll
    for (int ks = 0; ks < 8; ks++)
      a[af][ks] = *reinterpret_cast<const short8*>(qrow + ks * 32 + g * 8);
  }
#pragma unroll
  for (int af = 0; af < 2; af++)
#pragma unroll
    for (int ks = 0; ks < 8; ks++)
      asm volatile("" : "+v"(a[af][ks]));

  float m[2][4], lsum[2][4];
#pragma unroll
  for (int af = 0; af < 2; af++)
#pragma unroll
    for (int r = 0; r < 4; r++) { m[af][r] = kNegInf; lsum[af][r] = 0.f; }

  // diagonal tile index within this chunk for this wave, or -1
  const int ctd = (kc == (rt >> 2)) ? ((rt & 3) * 4 + w) : -1;

  __syncthreads();

  for (int ct = 0; ct < 16; ct++) {
    const int cur = ct & 1;
    if (ct + 1 < 16) stage16(ksrc + (size_t)(ct + 1) * 16384, kt[cur ^ 1], tid);

    const char* lb = kt[cur];
    f32x4 acc[2][2];
#pragma unroll
    for (int af = 0; af < 2; af++)
#pragma unroll
      for (int cf = 0; cf < 2; cf++) acc[af][cf] = f32x4{0.f, 0.f, 0.f, 0.f};

#pragma unroll
    for (int ks = 0; ks < 8; ks++) {
#pragma unroll
      for (int cf = 0; cf < 2; cf++) {
        const int row = cf * 16 + li;   // K-row (negative index in tile), 0..31
        const int off = row * 512 + ((ks * 64 + g * 16) ^ ((row & 15) << 4));
        short8 bf = *reinterpret_cast<const short8*>(lb + off);
        acc[0][cf] = __builtin_amdgcn_mfma_f32_16x16x32_bf16(a[0][ks], bf,
                                                             acc[0][cf], 0, 0, 0);
        acc[1][cf] = __builtin_amdgcn_mfma_f32_16x16x32_bf16(a[1][ks], bf,
                                                             acc[1][cf], 0, 0, 0);
      }
    }

    // diagonal: capture positive logit (full-D dot), then mask.
    if (ct == ctd) {
#pragma unroll
      for (int af = 0; af < 2; af++)
#pragma unroll
        for (int r = 0; r < 4; r++)
          if (li == g * 4 + r) {
            pp[b * PN + R0 + w * 32 + af * 16 + g * 4 + r] = acc[af][af][r];
            acc[af][af][r] = kMask2;
          }
    }

    // per-lane online logsumexp update
#pragma unroll
    for (int af = 0; af < 2; af++)
#pragma unroll
      for (int r = 0; r < 4; r++) {
        float v0 = acc[af][0][r], v1 = acc[af][1][r];
        float t0 = fmaxf(v0, v1);
        float mo = m[af][r];
        float mn = fmaxf(mo, t0);
        lsum[af][r] = lsum[af][r] * fexp2(mo - mn) + fexp2(v0 - mn) + fexp2(v1 - mn);
        m[af][r] = mn;
      }
    __syncthreads();
  }

  // merge 16 li-lanes per row, write chunk-partial LSE
#pragma unroll
  for (int af = 0; af < 2; af++)
#pragma unroll
    for (int r = 0; r < 4; r++) {
      float m_ = m[af][r], l_ = lsum[af][r];
#pragma unroll
      for (int off = 1; off < 16; off <<= 1) {
        float mo = __shfl_xor(m_, off, 64);
        float lo = __shfl_xor(l_, off, 64);
        float mn = fmaxf(m_, mo);
        l_ = l_ * fexp2(m_ - mn) + lo * fexp2(mo - mn);
        m_ = mn;
      }
      if (li == 0) {
        const int rowg = b * PN + R0 + w * 32 + af * 16 + g * 4 + r;
        pl[kc * NP + rowg] = m_ + flog2(l_);
      }
    }
}

// ================== combine: NC partials + pos -> loss ==================
template <int NC>
__global__ void k_combine(const float* __restrict__ pl,
                          const float* __restrict__ pp,
                          float* __restrict__ out) {
  const int i = blockIdx.x * blockDim.x + threadIdx.x;
  if (i >= NP) return;
  float mm = kNegInf;
  float v[NC];
#pragma unroll
  for (int c = 0; c < NC; c++) { v[c] = pl[c * NP + i]; mm = fmaxf(mm, v[c]); }
  float s = 0.f;
#pragma unroll
  for (int c = 0; c < NC; c++) s += fexp2(v[c] - mm);
  float lse = mm + flog2(s);
  float p = pp[i];
  float mn = fmaxf(lse, p);
  float la = mn + flog2(fexp2(lse - mn) + fexp2(p - mn));
  out[i] = (la - p) * kLn2;
}

// ================== fallback A: round-6 kernel (reads f32 Q) ==================
__global__ __launch_bounds__(256, 4) void k_nce32(
    const float* __restrict__ fq, const unsigned short* __restrict__ kb,
    float* __restrict__ pl, float* __restrict__ pp) {
  __shared__ __align__(16) char kt[2][32 * 512];

  const int blk = blockIdx.x;
  const int b   = blk & 3;
  const int rt  = (blk >> 2) & 31;
  const int kc  = blk >> 7;
  const int R0  = rt * 128;
  const int C0  = kc * 512;
  const int tid = threadIdx.x;
  const int w   = tid >> 6;
  const int l   = tid & 63;
  const int g   = l >> 4;
  const int li  = l & 15;

  const char* ksrc = reinterpret_cast<const char*>(kb) +
                     ((size_t)b * PN + C0) * 512;
  stage16(ksrc, kt[0], tid);

  short8 a[2][8];
#pragma unroll
  for (int af = 0; af < 2; af++) {
    const float* qrow = fq + ((size_t)(b * PN + R0 + w * 32 + af * 16 + li)) * DD;
#pragma unroll
    for (int ks = 0; ks < 8; ks++) {
      const float* p = qrow + ks * 32 + g * 8;
      float4 v0 = *reinterpret_cast<const float4*>(p);
      float4 v1 = *reinterpret_cast<const float4*>(p + 4);
      a[af][ks][0] = (short)f2bf(v0.x * kScale); a[af][ks][1] = (short)f2bf(v0.y * kScale);
      a[af][ks][2] = (short)f2bf(v0.z * kScale); a[af][ks][3] = (short)f2bf(v0.w * kScale);
      a[af][ks][4] = (short)f2bf(v1.x * kScale); a[af][ks][5] = (short)f2bf(v1.y * kScale);
      a[af][ks][6] = (short)f2bf(v1.z * kScale); a[af][ks][7] = (short)f2bf(v1.w * kScale);
    }
  }

  float m[2][4], lsum[2][4];
#pragma unroll
  for (int af = 0; af < 2; af++)
#pragma unroll
    for (int r = 0; r < 4; r++) { m[af][r] = kNegInf; lsum[af][r] = 0.f; }

  const int ctd = (kc == (rt >> 2)) ? ((rt & 3) * 4 + w) : -1;
  __syncthreads();

  for (int ct = 0; ct < 16; ct++) {
    const int cur = ct & 1;
    if (ct + 1 < 16) stage16(ksrc + (size_t)(ct + 1) * 16384, kt[cur ^ 1], tid);

    const char* lb = kt[cur];
    f32x4 acc[2][2];
#pragma unroll
    for (int af = 0; af < 2; af++)
#pragma unroll
      for (int cf = 0; cf < 2; cf++) acc[af][cf] = f32x4{0.f, 0.f, 0.f, 0.f};

#pragma unroll
    for (int ks = 0; ks < 8; ks++) {
#pragma unroll
      for (int cf = 0; cf < 2; cf++) {
        const int row = cf * 16 + li;
        const int off = row * 512 + ((ks * 64 + g * 16) ^ ((row & 15) << 4));
        short8 bf = *reinterpret_cast<const short8*>(lb + off);
        acc[0][cf] = __builtin_amdgcn_mfma_f32_16x16x32_bf16(a[0][ks], bf, acc[0][cf], 0, 0, 0);
        acc[1][cf] = __builtin_amdgcn_mfma_f32_16x16x32_bf16(a[1][ks], bf, acc[1][cf], 0, 0, 0);
      }
    }

    if (ct == ctd) {
#pragma unroll
      for (int af = 0; af < 2; af++)
#pragma unroll
        for (int r = 0; r < 4; r++)
          if (li == g * 4 + r) {
            pp[b * PN + R0 + w * 32 + af * 16 + g * 4 + r] = acc[af][af][r];
            acc[af][af][r] = kMask2;
          }
    }

#pragma unroll
    for (int af = 0; af < 2; af++)
#pragma unroll
      for (int r = 0; r < 4; r++) {
        float v0 = acc[af][0][r], v1 = acc[af][1][r];
        float t0 = fmaxf(v0, v1);
        float mo = m[af][r];
        float mn = fmaxf(mo, t0);
        lsum[af][r] = lsum[af][r] * fexp2(mo - mn) + fexp2(v0 - mn) + fexp2(v1 - mn);
        m[af][r] = mn;
      }
    __syncthreads();
  }

#pragma unroll
  for (int af = 0; af < 2; af++)
#pragma unroll
    for (int r = 0; r < 4; r++) {
      float m_ = m[af][r], l_ = lsum[af][r];
#pragma unroll
      for (int off = 1; off < 16; off <<= 1) {
        float mo = __shfl_xor(m_, off, 64);
        float lo = __shfl_xor(l_, off, 64);
        float mn = fmaxf(m_, mo);
        l_ = l_ * fexp2(m_ - mn) + lo * fexp2(mo - mn);
        m_ = mn;
      }
      if (li == 0) {
        const int rowg = b * PN + R0 + w * 32 + af * 16 + g * 4 + r;
        pl[kc * NP + rowg] = m_ + flog2(l_);
      }
    }
}

// ================== fallback B: single-pass (needs only 8 MB ws) ==================
__global__ __launch_bounds__(256) void k_nce_full(const float* __restrict__ fq,
                                                  const unsigned short* __restrict__ kb,
                                                  float* __restrict__ out) {
  __shared__ __align__(16) char kt[2][64 * 512];
  const int blk = blockIdx.x;
  const int b = blk & 3, rt = blk >> 2;
  const int R0 = rt * 64;
  const int tid = threadIdx.x;
  const int w = tid >> 6, l = tid & 63, g = l >> 4, li = l & 15;

  const float* qrow = fq + ((size_t)(b * PN + R0 + w * 16 + li)) * DD;
  short8 a[8];
#pragma unroll
  for (int ks = 0; ks < 8; ks++) {
    const float* p = qrow + ks * 32 + g * 8;
    float4 v0 = *reinterpret_cast<const float4*>(p);
    float4 v1 = *reinterpret_cast<const float4*>(p + 4);
    a[ks][0] = (short)f2bf(v0.x * kScale); a[ks][1] = (short)f2bf(v0.y * kScale);
    a[ks][2] = (short)f2bf(v0.z * kScale); a[ks][3] = (short)f2bf(v0.w * kScale);
    a[ks][4] = (short)f2bf(v1.x * kScale); a[ks][5] = (short)f2bf(v1.y * kScale);
    a[ks][6] = (short)f2bf(v1.z * kScale); a[ks][7] = (short)f2bf(v1.w * kScale);
  }
  float m[4], lsum[4], pos[4];
#pragma unroll
  for (int r = 0; r < 4; r++) { m[r] = kNegInf; lsum[r] = 0.f; pos[r] = kNegInf; }
  const char* ksrc = reinterpret_cast<const char*>(kb + (size_t)b * PN * DD);
  stage_tile(ksrc, kt[0], tid);
  __syncthreads();
  for (int ct = 0; ct < 64; ct++) {
    const int cur = ct & 1;
    if (ct + 1 < 64) stage_tile(ksrc + (size_t)(ct + 1) * 32768, kt[cur ^ 1], tid);
    const char* lb = kt[cur];
    f32x4 acc[4];
#pragma unroll
    for (int cf = 0; cf < 4; cf++) acc[cf] = f32x4{0.f, 0.f, 0.f, 0.f};
#pragma unroll
    for (int ks = 0; ks < 8; ks++) {
#pragma unroll
      for (int cf = 0; cf < 4; cf++) {
        const int row = cf * 16 + li;
        const int off = row * 512 + ((ks * 64 + g * 16) ^ ((row & 15) << 4));
        short8 bf = *reinterpret_cast<const short8*>(lb + off);
        acc[cf] = __builtin_amdgcn_mfma_f32_16x16x32_bf16(a[ks], bf, acc[cf], 0, 0, 0);
      }
    }
    if (ct == rt) {
#pragma unroll
      for (int cf = 0; cf < 4; cf++)
        if (cf == w) {
#pragma unroll
          for (int r = 0; r < 4; r++)
            if (li == g * 4 + r) { pos[r] = acc[cf][r]; acc[cf][r] = kMask2; }
        }
    }
#pragma unroll
    for (int r = 0; r < 4; r++) {
      float t0 = fmaxf(fmaxf(acc[0][r], acc[1][r]), fmaxf(acc[2][r], acc[3][r]));
      float mo = m[r];
      float mn = fmaxf(mo, t0);
      float s = fexp2(acc[0][r] - mn) + fexp2(acc[1][r] - mn) +
                fexp2(acc[2][r] - mn) + fexp2(acc[3][r] - mn);
      lsum[r] = lsum[r] * fexp2(mo - mn) + s;
      m[r] = mn;
    }
    __syncthreads();
  }
#pragma unroll
  for (int r = 0; r < 4; r++) {
    float m_ = m[r], l_ = lsum[r], p_ = pos[r];
#pragma unroll
    for (int off = 1; off < 16; off <<= 1) {
      float mo = __shfl_xor(m_, off, 64);
      float lo = __shfl_xor(l_, off, 64);
      float po = __shfl_xor(p_, off, 64);
      float mn = fmaxf(m_, mo);
      l_ = l_ * fexp2(m_ - mn) + lo * fexp2(mo - mn);
      m_ = mn;
      p_ = fmaxf(p_, po);
    }
    float mn  = fmaxf(m_, p_);
    float lse = mn + flog2(l_ * fexp2(m_ - mn) + fexp2(p_ - mn));
    if (li == 0) out[b * PN + R0 + w * 16 + g * 4 + r] = (lse - p_) * kLn2;
  }
}

extern "C" void kernel_launch(void* const* d_in, const int* in_sizes, int n_in,
                              void* d_out, int out_size, void* d_ws, size_t ws_size,
                              hipStream_t stream) {
  const float* fq = (const float*)d_in[0];
  const float* fk = (const float*)d_in[1];
  float* out = (float*)d_out;
  const size_t bufBytes = (size_t)NP * DD * 2;         // 8388608 per bf16 buffer
  const size_t ppBytes  = (size_t)NP * 4;              // 65536
  const size_t pl8Bytes = (size_t)8 * NP * 4;          // 524288
  const int n4each = (NP * DD) / 4;                    // 1048576

  if (ws_size >= 2 * bufBytes + pl8Bytes + ppBytes) {
    // main path: qb + kb pre-converted
    unsigned short* qb = (unsigned short*)d_ws;
    unsigned short* kb = (unsigned short*)((char*)d_ws + bufBytes);
    float* pl = (float*)((char*)d_ws + 2 * bufBytes);
    float* pp = (float*)((char*)d_ws + 2 * bufBytes + pl8Bytes);
    hipLaunchKernelGGL(k_convert2, dim3((2 * n4each) / 256), dim3(256), 0, stream,
                       fq, fk, qb, kb, n4each);
    hipLaunchKernelGGL(k_nceQ, dim3(1024), dim3(256), 0, stream, qb, kb, pl, pp);
    hipLaunchKernelGGL(k_combine<8>, dim3(NP / 256), dim3(256), 0, stream, pl, pp, out);
  } else if (ws_size >= bufBytes + pl8Bytes + ppBytes) {
    unsigned short* kb = (unsigned short*)d_ws;
    float* pl = (float*)((char*)d_ws + bufBytes);
    float* pp = (float*)((char*)d_ws + bufBytes + pl8Bytes);
    hipLaunchKernelGGL(k_convert, dim3(n4each / 256), dim3(256), 0, stream, fk, kb, n4each);
    hipLaunchKernelGGL(k_nce32, dim3(1024), dim3(256), 0, stream, fq, kb, pl, pp);
    hipLaunchKernelGGL(k_combine<8>, dim3(NP / 256), dim3(256), 0, stream, pl, pp, out);
  } else {
    unsigned short* kb = (unsigned short*)d_ws;
    hipLaunchKernelGGL(k_convert, dim3(n4each / 256), dim3(256), 0, stream, fk, kb, n4each);
    hipLaunchKernelGGL(k_nce_full, dim3(BATCH * (PN / 64)), dim3(256), 0, stream,
                       fq, kb, out);
  }
}